// Round 1
// baseline (157.649 us; speedup 1.0000x reference)
//
#include <hip/hip_runtime.h>
#include <hip/hip_bf16.h>
#include <cstdint>
#include <cstddef>

#define NB 8
#define NS 1024
#define ND 96
#define NG 8
#define NPAIR (ND*ND)        // 9216
#define BSTRIDE (NS*ND)      // 98304 floats per batch
#define ROWS (NB*NS)         // 8192

// ---------------------------------------------------------------------------
// K1a: Z0[b,s,i] = sum_j x[b,s,j] * M[i,j]
// lane = output column i (96 threads); M row held in 96 VGPRs; x row is
// wave-uniform -> compiler emits s_load + v_fma with SGPR operand.
// ---------------------------------------------------------------------------
__global__ __launch_bounds__(96) void k1a_proj(
    const float* __restrict__ x, const float* __restrict__ M,
    float* __restrict__ Z0)
{
    __shared__ float M_lds[96][97];   // +1 pad: conflict-free column reads
    const int t = threadIdx.x;        // 0..95 == output feature i
    const int R0 = blockIdx.x * 16;   // 16 (b,s) rows per block

    // stage M coalesced (2304 float4)
    for (int k = 0; k < 24; ++k) {
        int m = t + 96 * k;
        int i = m / 24, j0 = (m % 24) * 4;
        float4 v = *(const float4*)(M + i * 96 + j0);
        M_lds[i][j0]   = v.x; M_lds[i][j0+1] = v.y;
        M_lds[i][j0+2] = v.z; M_lds[i][j0+3] = v.w;
    }
    __syncthreads();

    float mreg[96];
    #pragma unroll
    for (int j = 0; j < 96; ++j) mreg[j] = M_lds[t][j];

    for (int r = 0; r < 16; ++r) {
        const float* xr = x + (size_t)(R0 + r) * 96;  // wave-uniform address
        float a0 = 0.f, a1 = 0.f, a2 = 0.f, a3 = 0.f;
        #pragma unroll
        for (int j = 0; j < 96; j += 4) {
            a0 = fmaf(xr[j+0], mreg[j+0], a0);
            a1 = fmaf(xr[j+1], mreg[j+1], a1);
            a2 = fmaf(xr[j+2], mreg[j+2], a2);
            a3 = fmaf(xr[j+3], mreg[j+3], a3);
        }
        Z0[(size_t)(R0 + r) * 96 + t] = (a0 + a1) + (a2 + a3);
    }
}

// ---------------------------------------------------------------------------
// K1b: LayerNorm rows of Z0 -> Z.  One wave per row (96 elems in 1.5 loads).
// ---------------------------------------------------------------------------
__global__ __launch_bounds__(256) void k1b_ln(
    const float* __restrict__ Z0, const float* __restrict__ gamma,
    const float* __restrict__ beta, float* __restrict__ Z)
{
    const int l = threadIdx.x & 63;
    const int w = threadIdx.x >> 6;
    const int row = blockIdx.x * 4 + w;
    const float* zr = Z0 + (size_t)row * 96;
    float v1 = zr[l];
    float v2 = (l < 32) ? zr[64 + l] : 0.f;
    float s1 = v1 + v2;
    float s2 = v1 * v1 + v2 * v2;
    #pragma unroll
    for (int off = 32; off; off >>= 1) {
        s1 += __shfl_xor(s1, off, 64);
        s2 += __shfl_xor(s2, off, 64);
    }
    float mu  = s1 * (1.f / 96.f);
    float var = s2 * (1.f / 96.f) - mu * mu;
    float rs  = rsqrtf(var + 1e-5f);
    float* zo = Z + (size_t)row * 96;
    zo[l] = (v1 - mu) * rs * gamma[l] + beta[l];
    if (l < 32) zo[64 + l] = (v2 - mu) * rs * gamma[64 + l] + beta[64 + l];
}

// ---------------------------------------------------------------------------
// KW: Wt[s][j*96+i] = bf16( sum_g P[i,j,g] * cos(2*pi*s / ((i*96+j)*8+g+2)) )
// Chebyshev recurrence over s (2 FMA per g per s) seeded by cospif per
// 64-step chunk. Thread p = j*96+i -> stores are lane-consecutive.
// ---------------------------------------------------------------------------
__global__ __launch_bounds__(256) void kw_basis(
    const float* __restrict__ P, __hip_bfloat16* __restrict__ Wt)
{
    const int p = blockIdx.x * 256 + threadIdx.x;  // 0..9215 = j*96+i
    const int i = p % 96, j = p / 96;
    const int s0 = blockIdx.y * 64;
    const int base = (i * 96 + j) * 8;             // period = base + g + 2

    float Pv[8], c[8], cp[8], tc1[8];
    {
        float4 a = *(const float4*)(P + base);
        float4 b = *(const float4*)(P + base + 4);
        Pv[0]=a.x; Pv[1]=a.y; Pv[2]=a.z; Pv[3]=a.w;
        Pv[4]=b.x; Pv[5]=b.y; Pv[6]=b.z; Pv[7]=b.w;
    }
    #pragma unroll
    for (int g = 0; g < 8; ++g) {
        float pf  = (float)(base + g + 2);
        float inv = 1.0f / pf;
        float c1  = cospif(2.0f * inv);
        tc1[g] = c1 + c1;
        c[g]  = cospif(2.0f * (float)s0 * inv);
        cp[g] = cospif(2.0f * (float)(s0 - 1) * inv);  // cos even: s0=0 ok
    }
    __hip_bfloat16* op = Wt + (size_t)s0 * NPAIR + p;
    for (int ss = 0; ss < 64; ++ss) {
        float w = 0.f;
        #pragma unroll
        for (int g = 0; g < 8; ++g) w = fmaf(Pv[g], c[g], w);
        *op = __float2bfloat16(w);
        op += NPAIR;
        #pragma unroll
        for (int g = 0; g < 8; ++g) {
            float cn = fmaf(tc1[g], c[g], -cp[g]);
            cp[g] = c[g]; c[g] = cn;
        }
    }
}

// ---------------------------------------------------------------------------
// KT: V[b,s,i] = Z0[b,s,i] + sum_j Z[b,s,j] * Wt[s][j*96+i]
// One block per s; lane = i; Z reads wave-uniform (scalar); W coalesced bf16.
// ---------------------------------------------------------------------------
__global__ __launch_bounds__(96) void kt_apply(
    const float* __restrict__ Z, const float* __restrict__ Z0,
    const __hip_bfloat16* __restrict__ Wt, float* __restrict__ V)
{
    const int i = threadIdx.x;
    const int s = blockIdx.x;
    float acc[8] = {0.f,0.f,0.f,0.f,0.f,0.f,0.f,0.f};
    const __hip_bfloat16* wrow = Wt + (size_t)s * NPAIR + i;
    const float* zs = Z + (size_t)s * 96;
    #pragma unroll 4
    for (int j = 0; j < 96; ++j) {
        float w = __bfloat162float(wrow[j * 96]);
        #pragma unroll
        for (int bb = 0; bb < 8; ++bb)
            acc[bb] = fmaf(zs[(size_t)bb * BSTRIDE + j], w, acc[bb]);
    }
    #pragma unroll
    for (int bb = 0; bb < 8; ++bb) {
        size_t o = (size_t)bb * BSTRIDE + (size_t)s * 96 + i;
        V[o] = acc[bb] + Z0[o];
    }
}

// ---------------------------------------------------------------------------
// K3: Part[sb][b][t][i] = sum_{s in sb-range} V[b,s,i] * Linker[s,t]
// 8x8 register tile, 32-s LDS chunks, s-split x8 into fp32 partials.
// ---------------------------------------------------------------------------
__global__ __launch_bounds__(192) void k3_linker(
    const float* __restrict__ V, const float* __restrict__ L,
    float* __restrict__ Part)
{
    __shared__ float V_t[32][96];
    __shared__ float L_t[32][128];
    const int t  = threadIdx.x;
    const int T0 = blockIdx.x * 128;   // 8 t-tiles of 128
    const int b  = blockIdx.y;         // 0..7
    const int sb = blockIdx.z;         // 0..7 s-split
    const int ig = t % 12;             // i0 = 8*ig
    const int tg = t / 12;             // tc0 = 8*tg (0..15)

    float acc[8][8];
    #pragma unroll
    for (int a = 0; a < 8; ++a)
        #pragma unroll
        for (int cc = 0; cc < 8; ++cc) acc[a][cc] = 0.f;

    for (int ch = 0; ch < 4; ++ch) {
        const int s0 = sb * 128 + ch * 32;
        // stage V chunk: 768 float4
        #pragma unroll
        for (int k = 0; k < 4; ++k) {
            int m = t + k * 192;
            int sr = m / 24, c0 = (m % 24) * 4;
            float4 v = *(const float4*)(V + (size_t)b * BSTRIDE + (size_t)(s0 + sr) * 96 + c0);
            *(float4*)&V_t[sr][c0] = v;
        }
        // stage L chunk: 1024 float4
        #pragma unroll
        for (int k = 0; k < 6; ++k) {
            int m = t + k * 192;
            if (m < 1024) {
                int sr = m / 32, c0 = (m % 32) * 4;
                float4 v = *(const float4*)(L + (size_t)(s0 + sr) * 1024 + T0 + c0);
                *(float4*)&L_t[sr][c0] = v;
            }
        }
        __syncthreads();
        for (int ss = 0; ss < 32; ++ss) {
            float4 v0 = *(const float4*)&V_t[ss][ig * 8];
            float4 v1 = *(const float4*)&V_t[ss][ig * 8 + 4];
            float4 l0 = *(const float4*)&L_t[ss][tg * 8];
            float4 l1 = *(const float4*)&L_t[ss][tg * 8 + 4];
            float vv[8] = {v0.x,v0.y,v0.z,v0.w,v1.x,v1.y,v1.z,v1.w};
            float ll[8] = {l0.x,l0.y,l0.z,l0.w,l1.x,l1.y,l1.z,l1.w};
            #pragma unroll
            for (int a = 0; a < 8; ++a)
                #pragma unroll
                for (int cc = 0; cc < 8; ++cc)
                    acc[a][cc] = fmaf(ll[a], vv[cc], acc[a][cc]);
        }
        __syncthreads();
    }
    float* po = Part + (size_t)sb * (NB * BSTRIDE) + (size_t)b * BSTRIDE;
    #pragma unroll
    for (int a = 0; a < 8; ++a) {
        int tc = T0 + tg * 8 + a;
        #pragma unroll
        for (int cc = 0; cc < 8; cc += 4) {
            float4 w4 = {acc[a][cc], acc[a][cc+1], acc[a][cc+2], acc[a][cc+3]};
            *(float4*)(po + (size_t)tc * 96 + ig * 8 + cc) = w4;
        }
    }
}

// ---------------------------------------------------------------------------
// K4: out = sum over 8 s-split partials
// ---------------------------------------------------------------------------
__global__ __launch_bounds__(256) void k4_reduce(
    const float* __restrict__ Part, float* __restrict__ out)
{
    const int e4 = blockIdx.x * 256 + threadIdx.x;  // 196608 float4
    const float4* p = (const float4*)Part;
    float4 a = p[e4];
    #pragma unroll
    for (int k = 1; k < 8; ++k) {
        float4 bb = p[(size_t)k * 196608 + e4];
        a.x += bb.x; a.y += bb.y; a.z += bb.z; a.w += bb.w;
    }
    ((float4*)out)[e4] = a;
}

extern "C" void kernel_launch(void* const* d_in, const int* in_sizes, int n_in,
                              void* d_out, int out_size, void* d_ws, size_t ws_size,
                              hipStream_t stream)
{
    const float* x     = (const float*)d_in[0];
    const float* M     = (const float*)d_in[1];
    const float* P     = (const float*)d_in[2];
    const float* Lnk   = (const float*)d_in[3];
    const float* gamma = (const float*)d_in[4];
    const float* beta  = (const float*)d_in[5];
    float* out = (float*)d_out;

    uint8_t* ws = (uint8_t*)d_ws;
    __hip_bfloat16* Wt = (__hip_bfloat16*)ws;                   // 18,874,368 B
    float* Z0   = (float*)(ws + 18874368);                      //  3,145,728 B
    float* Z    = Z0 + 786432;                                  //  3,145,728 B
    float* V    = Z  + 786432;                                  //  3,145,728 B
    float* Part = V  + 786432;                                  // 25,165,824 B  (total ~51 MB)

    k1a_proj <<<512,  96, 0, stream>>>(x, M, Z0);
    k1b_ln   <<<2048, 256, 0, stream>>>(Z0, gamma, beta, Z);
    kw_basis <<<dim3(36, 16), 256, 0, stream>>>(P, Wt);
    kt_apply <<<1024, 96, 0, stream>>>(Z, Z0, Wt, V);
    k3_linker<<<dim3(8, 8, 8), 192, 0, stream>>>(V, Lnk, Part);
    k4_reduce<<<768, 256, 0, stream>>>(Part, out);
}

// Round 2
// 144.588 us; speedup vs baseline: 1.0903x; 1.0903x over previous
//
#include <hip/hip_runtime.h>
#include <hip/hip_bf16.h>
#include <cstdint>
#include <cstddef>

#define NB 8
#define NS 1024
#define ND 96
#define NPAIR (ND*ND)        // 9216
#define BSTRIDE (NS*ND)      // 98304 floats per batch

typedef __attribute__((ext_vector_type(8))) short short8;
typedef __attribute__((ext_vector_type(4))) float f32x4;

__device__ __forceinline__ uint16_t f2bf(float x) {
    uint32_t u = __float_as_uint(x);
    uint32_t r = (u + 0x7FFF + ((u >> 16) & 1)) >> 16;   // RNE
    return (uint16_t)r;
}
__device__ __forceinline__ float bf2f(uint16_t b) {
    uint32_t u = ((uint32_t)b) << 16;
    return __uint_as_float(u);
}

// ---------------------------------------------------------------------------
// K1a: Z0[b,s,i] = sum_j x[b,s,j] * M[i,j]   (lane = i, M row in VGPRs,
// x row wave-uniform -> scalar loads)
// ---------------------------------------------------------------------------
__global__ __launch_bounds__(96) void k1a_proj(
    const float* __restrict__ x, const float* __restrict__ M,
    float* __restrict__ Z0)
{
    __shared__ float M_lds[96][97];
    const int t = threadIdx.x;
    const int R0 = blockIdx.x * 16;

    for (int k = 0; k < 24; ++k) {
        int m = t + 96 * k;
        int i = m / 24, j0 = (m % 24) * 4;
        float4 v = *(const float4*)(M + i * 96 + j0);
        M_lds[i][j0]   = v.x; M_lds[i][j0+1] = v.y;
        M_lds[i][j0+2] = v.z; M_lds[i][j0+3] = v.w;
    }
    __syncthreads();

    float mreg[96];
    #pragma unroll
    for (int j = 0; j < 96; ++j) mreg[j] = M_lds[t][j];

    for (int r = 0; r < 16; ++r) {
        const float* xr = x + (size_t)(R0 + r) * 96;
        float a0 = 0.f, a1 = 0.f, a2 = 0.f, a3 = 0.f;
        #pragma unroll
        for (int j = 0; j < 96; j += 4) {
            a0 = fmaf(xr[j+0], mreg[j+0], a0);
            a1 = fmaf(xr[j+1], mreg[j+1], a1);
            a2 = fmaf(xr[j+2], mreg[j+2], a2);
            a3 = fmaf(xr[j+3], mreg[j+3], a3);
        }
        Z0[(size_t)(R0 + r) * 96 + t] = (a0 + a1) + (a2 + a3);
    }
}

// ---------------------------------------------------------------------------
// K1b: LayerNorm rows of Z0 -> Z.  One wave per row.
// ---------------------------------------------------------------------------
__global__ __launch_bounds__(256) void k1b_ln(
    const float* __restrict__ Z0, const float* __restrict__ gamma,
    const float* __restrict__ beta, float* __restrict__ Z)
{
    const int l = threadIdx.x & 63;
    const int w = threadIdx.x >> 6;
    const int row = blockIdx.x * 4 + w;
    const float* zr = Z0 + (size_t)row * 96;
    float v1 = zr[l];
    float v2 = (l < 32) ? zr[64 + l] : 0.f;
    float s1 = v1 + v2;
    float s2 = v1 * v1 + v2 * v2;
    #pragma unroll
    for (int off = 32; off; off >>= 1) {
        s1 += __shfl_xor(s1, off, 64);
        s2 += __shfl_xor(s2, off, 64);
    }
    float mu  = s1 * (1.f / 96.f);
    float var = s2 * (1.f / 96.f) - mu * mu;
    float rs  = rsqrtf(var + 1e-5f);
    float* zo = Z + (size_t)row * 96;
    zo[l] = (v1 - mu) * rs * gamma[l] + beta[l];
    if (l < 32) zo[64 + l] = (v2 - mu) * rs * gamma[64 + l] + beta[64 + l];
}

// ---------------------------------------------------------------------------
// KL: Lt[t][s] = bf16(Linker[s][t])   (64x64 LDS transpose tiles)
// ---------------------------------------------------------------------------
__global__ __launch_bounds__(256) void kl_cvt(
    const float* __restrict__ L, uint16_t* __restrict__ Lt)
{
    __shared__ float T[64][65];
    const int t = threadIdx.x;
    const int s0 = blockIdx.x * 64, t0 = blockIdx.y * 64;
    const int r = t >> 4, c = (t & 15) * 4;
    #pragma unroll
    for (int k = 0; k < 4; ++k) {
        int rr = r + k * 16;
        float4 v = *(const float4*)(L + (size_t)(s0 + rr) * 1024 + t0 + c);
        T[rr][c]   = v.x; T[rr][c+1] = v.y;
        T[rr][c+2] = v.z; T[rr][c+3] = v.w;
    }
    __syncthreads();
    #pragma unroll
    for (int k = 0; k < 4; ++k) {
        int tr = r + k * 16;
        uint32_t u01 = (uint32_t)f2bf(T[c+0][tr]) | ((uint32_t)f2bf(T[c+1][tr]) << 16);
        uint32_t u23 = (uint32_t)f2bf(T[c+2][tr]) | ((uint32_t)f2bf(T[c+3][tr]) << 16);
        uint2 o; o.x = u01; o.y = u23;
        *(uint2*)(Lt + (size_t)(t0 + tr) * 1024 + s0 + c) = o;
    }
}

// ---------------------------------------------------------------------------
// KW: Wt[s][i*96+j] = bf16( sum_g P[i,j,g]*cos(2*pi*s/(p*8+g+2)) ), p=i*96+j.
// Chebyshev recurrence over s, seeded with cospif per 64-s chunk.
// j-contiguous layout so KT can read 16B vectors.
// ---------------------------------------------------------------------------
__global__ __launch_bounds__(256) void kw_basis(
    const float* __restrict__ P, uint16_t* __restrict__ Wt)
{
    const int p = blockIdx.x * 256 + threadIdx.x;  // = i*96 + j
    const int s0 = blockIdx.y * 64;
    const int base = p * 8;                        // period = base + g + 2

    float Pv[8], c[8], cp[8], tc1[8];
    {
        float4 a = *(const float4*)(P + base);
        float4 b = *(const float4*)(P + base + 4);
        Pv[0]=a.x; Pv[1]=a.y; Pv[2]=a.z; Pv[3]=a.w;
        Pv[4]=b.x; Pv[5]=b.y; Pv[6]=b.z; Pv[7]=b.w;
    }
    #pragma unroll
    for (int g = 0; g < 8; ++g) {
        float pf  = (float)(base + g + 2);
        float inv = 1.0f / pf;
        float c1  = cospif(2.0f * inv);
        tc1[g] = c1 + c1;
        c[g]  = cospif(2.0f * (float)s0 * inv);
        cp[g] = cospif(2.0f * (float)(s0 - 1) * inv);
    }
    uint16_t* op = Wt + (size_t)s0 * NPAIR + p;
    for (int ss = 0; ss < 64; ++ss) {
        float w = 0.f;
        #pragma unroll
        for (int g = 0; g < 8; ++g) w = fmaf(Pv[g], c[g], w);
        *op = f2bf(w);
        op += NPAIR;
        #pragma unroll
        for (int g = 0; g < 8; ++g) {
            float cn = fmaf(tc1[g], c[g], -cp[g]);
            cp[g] = c[g]; c[g] = cn;
        }
    }
}

// ---------------------------------------------------------------------------
// KT: Vt[b][i][s] = bf16( Z0[b,s,i] + sum_j Z[b,s,j]*Wt[s][i*96+j] )
// One block per s; lane = i; W rows read as 16B vectors; Z wave-uniform.
// ---------------------------------------------------------------------------
__global__ __launch_bounds__(96) void kt_apply(
    const float* __restrict__ Z, const float* __restrict__ Z0,
    const uint16_t* __restrict__ Wt, uint16_t* __restrict__ Vt)
{
    const int i = threadIdx.x;
    const int s = blockIdx.x;
    float acc[8] = {0.f,0.f,0.f,0.f,0.f,0.f,0.f,0.f};
    const uint16_t* wrow = Wt + (size_t)s * NPAIR + i * 96;
    const float* zs = Z + (size_t)s * 96;
    for (int j0 = 0; j0 < 96; j0 += 8) {
        short8 w8 = *(const short8*)(wrow + j0);
        float w[8];
        #pragma unroll
        for (int jj = 0; jj < 8; ++jj) w[jj] = bf2f((uint16_t)w8[jj]);
        #pragma unroll
        for (int bb = 0; bb < 8; ++bb) {
            const float* zb = zs + (size_t)bb * BSTRIDE + j0;
            #pragma unroll
            for (int jj = 0; jj < 8; ++jj)
                acc[bb] = fmaf(zb[jj], w[jj], acc[bb]);
        }
    }
    #pragma unroll
    for (int bb = 0; bb < 8; ++bb) {
        size_t o = (size_t)bb * BSTRIDE + (size_t)s * 96 + i;
        Vt[((size_t)bb * 96 + i) * 1024 + s] = f2bf(acc[bb] + Z0[o]);
    }
}

// ---------------------------------------------------------------------------
// K3: Part[sb][b][t][i] = sum_{s in sb*256..} Lt[t][s]*Vt[b][i][s]
// MFMA 16x16x32 bf16, gemm_bt pattern (both operands K-major), no LDS.
// Wave = 16 t-rows x 96 i; block = 4 waves (64 t); grid (16,8,4).
// ---------------------------------------------------------------------------
__global__ __launch_bounds__(256) void k3_mfma(
    const uint16_t* __restrict__ Lt, const uint16_t* __restrict__ Vt,
    float* __restrict__ Part)
{
    const int lane = threadIdx.x & 63;
    const int wv   = threadIdx.x >> 6;
    const int m    = lane & 15;
    const int quad = lane >> 4;
    const int t0   = blockIdx.x * 64 + wv * 16;
    const int b    = blockIdx.y;
    const int sb   = blockIdx.z;

    const uint16_t* Lp = Lt + (size_t)(t0 + m) * 1024 + sb * 256 + quad * 8;
    const uint16_t* Vp = Vt + ((size_t)b * 96 + m) * 1024 + sb * 256 + quad * 8;

    f32x4 acc[6];
    #pragma unroll
    for (int ii = 0; ii < 6; ++ii) acc[ii] = (f32x4){0.f, 0.f, 0.f, 0.f};

    #pragma unroll 2
    for (int kc = 0; kc < 8; ++kc) {
        short8 a = *(const short8*)(Lp + kc * 32);
        short8 bf[6];
        #pragma unroll
        for (int ii = 0; ii < 6; ++ii)
            bf[ii] = *(const short8*)(Vp + (size_t)ii * 16 * 1024 + kc * 32);
        #pragma unroll
        for (int ii = 0; ii < 6; ++ii)
            acc[ii] = __builtin_amdgcn_mfma_f32_16x16x32_bf16(a, bf[ii], acc[ii], 0, 0, 0);
    }

    float* po = Part + ((size_t)sb * NB + b) * BSTRIDE;
    #pragma unroll
    for (int ii = 0; ii < 6; ++ii)
        #pragma unroll
        for (int r = 0; r < 4; ++r)
            po[(size_t)(t0 + quad * 4 + r) * 96 + ii * 16 + m] = acc[ii][r];
}

// ---------------------------------------------------------------------------
// K4: out = sum over 4 s-split partials
// ---------------------------------------------------------------------------
__global__ __launch_bounds__(256) void k4_reduce(
    const float* __restrict__ Part, float* __restrict__ out)
{
    const int e4 = blockIdx.x * 256 + threadIdx.x;  // 196608 float4
    const float4* p = (const float4*)Part;
    float4 a = p[e4];
    #pragma unroll
    for (int k = 1; k < 4; ++k) {
        float4 bb = p[(size_t)k * 196608 + e4];
        a.x += bb.x; a.y += bb.y; a.z += bb.z; a.w += bb.w;
    }
    ((float4*)out)[e4] = a;
}

extern "C" void kernel_launch(void* const* d_in, const int* in_sizes, int n_in,
                              void* d_out, int out_size, void* d_ws, size_t ws_size,
                              hipStream_t stream)
{
    const float* x     = (const float*)d_in[0];
    const float* M     = (const float*)d_in[1];
    const float* P     = (const float*)d_in[2];
    const float* Lnk   = (const float*)d_in[3];
    const float* gamma = (const float*)d_in[4];
    const float* beta  = (const float*)d_in[5];
    float* out = (float*)d_out;

    uint8_t* ws = (uint8_t*)d_ws;
    uint16_t* Wt  = (uint16_t*)ws;                        // [0, 18874368)
    float*    Z0  = (float*)(ws + 18874368);              // 3,145,728 B
    float*    Z   = (float*)(ws + 22020096);              // 3,145,728 B
    uint16_t* Lt  = (uint16_t*)(ws + 25165824);           // 2,097,152 B
    uint16_t* Vt  = (uint16_t*)(ws + 27262976);           // 1,572,864 B
    float*    Part= (float*)(ws + 28835840);              // 12,582,912 B (tot ~41.4 MB)

    k1a_proj <<<512,  96, 0, stream>>>(x, M, Z0);
    k1b_ln   <<<2048, 256, 0, stream>>>(Z0, gamma, beta, Z);
    kl_cvt   <<<dim3(16, 16), 256, 0, stream>>>(Lnk, Lt);
    kw_basis <<<dim3(36, 16), 256, 0, stream>>>(P, Wt);
    kt_apply <<<1024, 96, 0, stream>>>(Z, Z0, Wt, Vt);
    k3_mfma  <<<dim3(16, 8, 4), 256, 0, stream>>>(Lt, Vt, Part);
    k4_reduce<<<768, 256, 0, stream>>>(Part, out);
}

// Round 3
// 125.782 us; speedup vs baseline: 1.2534x; 1.1495x over previous
//
#include <hip/hip_runtime.h>
#include <hip/hip_bf16.h>
#include <cstdint>
#include <cstddef>

#define NB 8
#define NS 1024
#define ND 96
#define NPAIR (ND*ND)        // 9216
#define BSTRIDE (NS*ND)      // 98304 floats per batch

typedef __attribute__((ext_vector_type(8))) short short8;
typedef __attribute__((ext_vector_type(4))) float f32x4;

__device__ __forceinline__ uint16_t f2bf(float x) {
    uint32_t u = __float_as_uint(x);
    uint32_t r = (u + 0x7FFF + ((u >> 16) & 1)) >> 16;   // RNE
    return (uint16_t)r;
}
__device__ __forceinline__ float bf2f(uint16_t b) {
    uint32_t u = ((uint32_t)b) << 16;
    return __uint_as_float(u);
}

// ---------------------------------------------------------------------------
// K1 mega-kernel, 96 threads/block, 2304 blocks:
//   blocks [0,512):    Z0 = x@M^T + fused LayerNorm -> Z   (16 rows/block)
//   blocks [512,768):  Lt[t][s] = bf16(Linker[s][t])       (64x64 tiles)
//   blocks [768,2304): Wt[s][i*96+j] via Chebyshev cos recurrence
// All three phases are independent -> co-resident across CUs.
// ---------------------------------------------------------------------------
union SmemK1 {
    float M[96][97];                                   // 37.2 KB (max)
    struct { float zb[16][100]; float ps[16][6][2]; float stats[16][2]; } ln;
    struct { float T[64][65]; } kl;
};

__global__ __launch_bounds__(96) void k1_mega(
    const float* __restrict__ x, const float* __restrict__ M,
    const float* __restrict__ P, const float* __restrict__ L,
    const float* __restrict__ gamma, const float* __restrict__ beta,
    float* __restrict__ Z0, float* __restrict__ Z,
    uint16_t* __restrict__ Lt, uint16_t* __restrict__ Wt)
{
    __shared__ SmemK1 sm;
    const int t  = threadIdx.x;
    const int bx = blockIdx.x;

    if (bx < 512) {
        // ---------------- proj + LN ----------------
        const int R0 = bx * 16;
        // stage M coalesced
        for (int k = 0; k < 24; ++k) {
            int mm = t + 96 * k;
            int i = mm / 24, j0 = (mm % 24) * 4;
            float4 v = *(const float4*)(M + i * 96 + j0);
            sm.M[i][j0]   = v.x; sm.M[i][j0+1] = v.y;
            sm.M[i][j0+2] = v.z; sm.M[i][j0+3] = v.w;
        }
        __syncthreads();
        float mreg[96];
        #pragma unroll
        for (int j = 0; j < 96; ++j) mreg[j] = sm.M[t][j];
        __syncthreads();   // M region dead; ln region reuses it

        // phase A: 16 rows of Z0, staged in LDS
        for (int r = 0; r < 16; ++r) {
            const float* xr = x + (size_t)(R0 + r) * 96;  // wave-uniform
            float a0 = 0.f, a1 = 0.f, a2 = 0.f, a3 = 0.f;
            #pragma unroll
            for (int j = 0; j < 96; j += 4) {
                a0 = fmaf(xr[j+0], mreg[j+0], a0);
                a1 = fmaf(xr[j+1], mreg[j+1], a1);
                a2 = fmaf(xr[j+2], mreg[j+2], a2);
                a3 = fmaf(xr[j+3], mreg[j+3], a3);
            }
            float z = (a0 + a1) + (a2 + a3);
            sm.ln.zb[r][t] = z;
            Z0[(size_t)(R0 + r) * 96 + t] = z;
        }
        __syncthreads();
        // phase B: segmented partial sums (16 rows x 6 segs of 16)
        {
            const int row = t / 6, seg = t % 6;
            const float4* zp = (const float4*)&sm.ln.zb[row][seg * 16];
            float s1 = 0.f, s2 = 0.f;
            #pragma unroll
            for (int k = 0; k < 4; ++k) {
                float4 v = zp[k];
                s1 += v.x + v.y + v.z + v.w;
                s2 += v.x*v.x + v.y*v.y + v.z*v.z + v.w*v.w;
            }
            sm.ln.ps[row][seg][0] = s1;
            sm.ln.ps[row][seg][1] = s2;
        }
        __syncthreads();
        // phase C: per-row stats
        if (t < 16) {
            float s1 = 0.f, s2 = 0.f;
            #pragma unroll
            for (int k = 0; k < 6; ++k) {
                s1 += sm.ln.ps[t][k][0];
                s2 += sm.ln.ps[t][k][1];
            }
            float mu  = s1 * (1.f / 96.f);
            float var = s2 * (1.f / 96.f) - mu * mu;
            sm.ln.stats[t][0] = mu;
            sm.ln.stats[t][1] = rsqrtf(var + 1e-5f);
        }
        __syncthreads();
        // phase D: normalize
        {
            float gm = gamma[t], bt = beta[t];
            for (int r = 0; r < 16; ++r) {
                float mu = sm.ln.stats[r][0], rs = sm.ln.stats[r][1];
                Z[(size_t)(R0 + r) * 96 + t] =
                    (sm.ln.zb[r][t] - mu) * rs * gm + bt;
            }
        }
        return;
    }

    if (bx < 768) {
        // ---------------- Linker transpose -> bf16 ----------------
        const int bx2 = bx - 512;
        const int s0 = (bx2 & 15) * 64, t0 = (bx2 >> 4) * 64;
        if (t < 64) {
            for (int r = 0; r < 64; ++r)
                sm.kl.T[r][t] = L[(size_t)(s0 + r) * 1024 + t0 + t];
        }
        __syncthreads();
        if (t < 64) {
            uint16_t* orow = Lt + (size_t)(t0 + t) * 1024 + s0;
            #pragma unroll
            for (int c4 = 0; c4 < 16; ++c4) {
                uint32_t u01 = (uint32_t)f2bf(sm.kl.T[c4*4+0][t]) |
                               ((uint32_t)f2bf(sm.kl.T[c4*4+1][t]) << 16);
                uint32_t u23 = (uint32_t)f2bf(sm.kl.T[c4*4+2][t]) |
                               ((uint32_t)f2bf(sm.kl.T[c4*4+3][t]) << 16);
                uint2 o; o.x = u01; o.y = u23;
                *(uint2*)(orow + c4 * 4) = o;
            }
        }
        return;
    }

    // ---------------- basis weights (Chebyshev over s) ----------------
    {
        const int idx = bx - 768;          // [0,1536)
        const int pb  = idx % 96;
        const int sc  = idx / 96;          // [0,16)
        const int p   = pb * 96 + t;       // = i*96 + j
        const int s0  = sc * 64;
        const int base = p * 8;            // period = base + g + 2

        float Pv[8], c[8], cp[8], tc1[8];
        {
            float4 a = *(const float4*)(P + base);
            float4 b = *(const float4*)(P + base + 4);
            Pv[0]=a.x; Pv[1]=a.y; Pv[2]=a.z; Pv[3]=a.w;
            Pv[4]=b.x; Pv[5]=b.y; Pv[6]=b.z; Pv[7]=b.w;
        }
        #pragma unroll
        for (int g = 0; g < 8; ++g) {
            float pf  = (float)(base + g + 2);
            float inv = 1.0f / pf;
            float c1  = cospif(2.0f * inv);
            tc1[g] = c1 + c1;
            c[g]  = cospif(2.0f * (float)s0 * inv);
            cp[g] = cospif(2.0f * (float)(s0 - 1) * inv);
        }
        uint16_t* op = Wt + (size_t)s0 * NPAIR + p;
        for (int ss = 0; ss < 64; ++ss) {
            float w = 0.f;
            #pragma unroll
            for (int g = 0; g < 8; ++g) w = fmaf(Pv[g], c[g], w);
            *op = f2bf(w);
            op += NPAIR;
            #pragma unroll
            for (int g = 0; g < 8; ++g) {
                float cn = fmaf(tc1[g], c[g], -cp[g]);
                cp[g] = c[g]; c[g] = cn;
            }
        }
    }
}

// ---------------------------------------------------------------------------
// KT: Vt[b][i][s] = bf16( Z0[b,s,i] + sum_j Z[b,s,j]*Wt[s][i*96+j] )
// One block per s; lane = i; W rows read as 16B vectors; Z wave-uniform.
// ---------------------------------------------------------------------------
__global__ __launch_bounds__(96) void kt_apply(
    const float* __restrict__ Z, const float* __restrict__ Z0,
    const uint16_t* __restrict__ Wt, uint16_t* __restrict__ Vt)
{
    const int i = threadIdx.x;
    const int s = blockIdx.x;
    float acc[8] = {0.f,0.f,0.f,0.f,0.f,0.f,0.f,0.f};
    const uint16_t* wrow = Wt + (size_t)s * NPAIR + i * 96;
    const float* zs = Z + (size_t)s * 96;
    for (int j0 = 0; j0 < 96; j0 += 8) {
        short8 w8 = *(const short8*)(wrow + j0);
        float w[8];
        #pragma unroll
        for (int jj = 0; jj < 8; ++jj) w[jj] = bf2f((uint16_t)w8[jj]);
        #pragma unroll
        for (int bb = 0; bb < 8; ++bb) {
            const float* zb = zs + (size_t)bb * BSTRIDE + j0;
            #pragma unroll
            for (int jj = 0; jj < 8; ++jj)
                acc[bb] = fmaf(zb[jj], w[jj], acc[bb]);
        }
    }
    #pragma unroll
    for (int bb = 0; bb < 8; ++bb) {
        size_t o = (size_t)bb * BSTRIDE + (size_t)s * 96 + i;
        Vt[((size_t)bb * 96 + i) * 1024 + s] = f2bf(acc[bb] + Z0[o]);
    }
}

// ---------------------------------------------------------------------------
// K3: out[b,t,i] = sum_{s=0..1023} Lt[t][s]*Vt[b][i][s]
// MFMA 16x16x32 bf16, both operands K-major, full K per wave, no partials.
// 128 thr (2 waves, t-tile 32), grid (32, 8) = 256 blocks.
// Depth-2 software pipeline on global loads.
// ---------------------------------------------------------------------------
__global__ __launch_bounds__(128) void k3_mfma(
    const uint16_t* __restrict__ Lt, const uint16_t* __restrict__ Vt,
    float* __restrict__ out)
{
    const int lane = threadIdx.x & 63;
    const int wv   = threadIdx.x >> 6;
    const int m    = lane & 15;
    const int quad = lane >> 4;
    const int t0   = blockIdx.x * 32 + wv * 16;
    const int b    = blockIdx.y;

    const uint16_t* Lp = Lt + (size_t)(t0 + m) * 1024 + quad * 8;
    const uint16_t* Vp = Vt + ((size_t)b * 96 + m) * 1024 + quad * 8;

    f32x4 acc[6];
    #pragma unroll
    for (int ii = 0; ii < 6; ++ii) acc[ii] = (f32x4){0.f, 0.f, 0.f, 0.f};

    short8 a = *(const short8*)Lp;
    short8 bv[6];
    #pragma unroll
    for (int ii = 0; ii < 6; ++ii)
        bv[ii] = *(const short8*)(Vp + (size_t)ii * 16 * 1024);

    for (int kc = 0; kc < 31; ++kc) {
        short8 an = *(const short8*)(Lp + (kc + 1) * 32);
        short8 bn[6];
        #pragma unroll
        for (int ii = 0; ii < 6; ++ii)
            bn[ii] = *(const short8*)(Vp + (size_t)ii * 16 * 1024 + (kc + 1) * 32);
        #pragma unroll
        for (int ii = 0; ii < 6; ++ii)
            acc[ii] = __builtin_amdgcn_mfma_f32_16x16x32_bf16(a, bv[ii], acc[ii], 0, 0, 0);
        a = an;
        #pragma unroll
        for (int ii = 0; ii < 6; ++ii) bv[ii] = bn[ii];
    }
    #pragma unroll
    for (int ii = 0; ii < 6; ++ii)
        acc[ii] = __builtin_amdgcn_mfma_f32_16x16x32_bf16(a, bv[ii], acc[ii], 0, 0, 0);

    float* po = out + (size_t)b * BSTRIDE;
    #pragma unroll
    for (int ii = 0; ii < 6; ++ii)
        #pragma unroll
        for (int r = 0; r < 4; ++r)
            po[(size_t)(t0 + quad * 4 + r) * 96 + ii * 16 + m] = acc[ii][r];
}

extern "C" void kernel_launch(void* const* d_in, const int* in_sizes, int n_in,
                              void* d_out, int out_size, void* d_ws, size_t ws_size,
                              hipStream_t stream)
{
    const float* x     = (const float*)d_in[0];
    const float* M     = (const float*)d_in[1];
    const float* P     = (const float*)d_in[2];
    const float* Lnk   = (const float*)d_in[3];
    const float* gamma = (const float*)d_in[4];
    const float* beta  = (const float*)d_in[5];
    float* out = (float*)d_out;

    uint8_t* ws = (uint8_t*)d_ws;
    uint16_t* Wt  = (uint16_t*)ws;                        // 18,874,368 B
    float*    Z0  = (float*)(ws + 18874368);              //  3,145,728 B
    float*    Z   = (float*)(ws + 22020096);              //  3,145,728 B
    uint16_t* Lt  = (uint16_t*)(ws + 25165824);           //  2,097,152 B
    uint16_t* Vt  = (uint16_t*)(ws + 27262976);           //  1,572,864 B  (~28.8 MB)

    k1_mega <<<2304, 96, 0, stream>>>(x, M, P, Lnk, gamma, beta, Z0, Z, Lt, Wt);
    kt_apply<<<1024, 96, 0, stream>>>(Z, Z0, Wt, Vt);
    k3_mfma <<<dim3(32, 8), 128, 0, stream>>>(Lt, Vt, out);
}